// Round 1
// baseline (19474.484 us; speedup 1.0000x reference)
//
#include <hip/hip_runtime.h>
#include <math.h>

#define NB 32
#define SEQ 197
#define WD 768
#define NH 12
#define HD 64
#define FF 3072
#define NL 12
#define ROWS (NB*SEQ)      // 6304
#define PROWS (NB*196)     // 6272
#define ATT_LD 208

__device__ __forceinline__ float wave_max(float v) {
  #pragma unroll
  for (int off = 32; off; off >>= 1) v = fmaxf(v, __shfl_xor(v, off));
  return v;
}
__device__ __forceinline__ float wave_sum(float v) {
  #pragma unroll
  for (int off = 32; off; off >>= 1) v += __shfl_xor(v, off);
  return v;
}

// ---------------------------------------------------------------------------
// Generic fp32 GEMM: C[M,N] = epilogue(A[M,K] @ B[K,N] + bias[N])
// EPI 0: none; 1: += residual R; 2: exact GELU.
// 128x128 tile, BK=16, 256 threads, 8x8 microtile.
// ---------------------------------------------------------------------------
template<int EPI>
__global__ __launch_bounds__(256) void gemm128(
    const float* __restrict__ A, const float* __restrict__ B,
    const float* __restrict__ bias, const float* __restrict__ R,
    float* __restrict__ C, int M, int N, int K)
{
  __shared__ float As[16][132];   // A^T tile: As[k][m], stride 132 (16B aligned, 2-way banks)
  __shared__ float Bs[16][132];
  const int tid = threadIdx.x;
  const int bm = blockIdx.y * 128;
  const int bn = blockIdx.x * 128;
  const int tx = tid & 15;
  const int ty = tid >> 4;
  const int arow = tid >> 1;          // 0..127
  const int acol = (tid & 1) * 8;     // 0 or 8
  const int brow = tid >> 4;          // 0..15
  const int bcol = (tid & 15) * 8;    // 0..120
  const bool aok = (bm + arow) < M;
  const float* Ap = A + (size_t)(bm + arow) * K + acol;
  const float* Bp = B + (size_t)brow * N + bn + bcol;
  float acc[8][8];
  #pragma unroll
  for (int i = 0; i < 8; ++i)
    #pragma unroll
    for (int j = 0; j < 8; ++j) acc[i][j] = 0.f;

  for (int k0 = 0; k0 < K; k0 += 16) {
    float4 a0 = {0,0,0,0}, a1 = {0,0,0,0};
    if (aok) {
      a0 = *(const float4*)(Ap + k0);
      a1 = *(const float4*)(Ap + k0 + 4);
    }
    const float4 b0 = *(const float4*)(Bp + (size_t)k0 * N);
    const float4 b1 = *(const float4*)(Bp + (size_t)k0 * N + 4);
    __syncthreads();
    As[acol+0][arow] = a0.x; As[acol+1][arow] = a0.y;
    As[acol+2][arow] = a0.z; As[acol+3][arow] = a0.w;
    As[acol+4][arow] = a1.x; As[acol+5][arow] = a1.y;
    As[acol+6][arow] = a1.z; As[acol+7][arow] = a1.w;
    *(float4*)&Bs[brow][bcol]   = b0;
    *(float4*)&Bs[brow][bcol+4] = b1;
    __syncthreads();
    #pragma unroll
    for (int kk = 0; kk < 16; ++kk) {
      float a[8], b[8];
      *(float4*)&a[0] = *(const float4*)&As[kk][ty*8];
      *(float4*)&a[4] = *(const float4*)&As[kk][ty*8+4];
      *(float4*)&b[0] = *(const float4*)&Bs[kk][tx*8];
      *(float4*)&b[4] = *(const float4*)&Bs[kk][tx*8+4];
      #pragma unroll
      for (int i = 0; i < 8; ++i)
        #pragma unroll
        for (int j = 0; j < 8; ++j)
          acc[i][j] = fmaf(a[i], b[j], acc[i][j]);
    }
  }
  #pragma unroll
  for (int i = 0; i < 8; ++i) {
    const int row = bm + ty*8 + i;
    if (row < M) {
      const size_t off = (size_t)row * N + bn + tx*8;
      float vb[8];
      #pragma unroll
      for (int j = 0; j < 8; ++j) vb[j] = acc[i][j] + bias[bn + tx*8 + j];
      if (EPI == 1) {
        #pragma unroll
        for (int j = 0; j < 8; ++j) vb[j] += R[off + j];
      }
      if (EPI == 2) {
        #pragma unroll
        for (int j = 0; j < 8; ++j)
          vb[j] = 0.5f * vb[j] * (1.f + erff(vb[j] * 0.70710678118654752f));
      }
      *(float4*)(C + off)     = *(const float4*)&vb[0];
      *(float4*)(C + off + 4) = *(const float4*)&vb[4];
    }
  }
}

// ---------------------------------------------------------------------------
// conv_w [768][768] (n,k) -> convT [768][768] (k,n)
// ---------------------------------------------------------------------------
__global__ void transpose_k(const float* __restrict__ in, float* __restrict__ out) {
  __shared__ float tile[32][33];
  const int bx = blockIdx.x * 32, by = blockIdx.y * 32;
  const int tx = threadIdx.x, ty = threadIdx.y;
  #pragma unroll
  for (int j = 0; j < 32; j += 8)
    tile[ty + j][tx] = in[(size_t)(by + ty + j) * 768 + bx + tx];
  __syncthreads();
  #pragma unroll
  for (int j = 0; j < 32; j += 8)
    out[(size_t)(bx + ty + j) * 768 + by + tx] = tile[tx][ty + j];
}

// ---------------------------------------------------------------------------
// im2col (stride = patch = 16 -> pure permutation)
// A[row, k], row = b*196 + py*14 + px, k = c*256 + ph*16 + pw
// ---------------------------------------------------------------------------
__global__ void im2col_k(const float* __restrict__ x, float* __restrict__ A) {
  const int idx = blockIdx.x * 256 + threadIdx.x;
  if (idx >= PROWS * WD) return;
  const int k = idx % WD;
  const int row = idx / WD;
  const int pw = k & 15, ph = (k >> 4) & 15, c = k >> 8;
  const int px = row % 14, py = (row / 14) % 14, b = row / 196;
  A[idx] = x[(size_t)((b*3 + c)*224 + py*16 + ph) * 224 + px*16 + pw];
}

// h[b,0,:] = cls + pe[0]; h[b,s,:] = tok[b,s-1,:] + pe[s]
__global__ void assemble_k(const float* __restrict__ tok, const float* __restrict__ cls,
                           const float* __restrict__ pe, float* __restrict__ h) {
  const int idx = blockIdx.x * 256 + threadIdx.x;
  if (idx >= ROWS * WD) return;
  const int w = idx % WD;
  const int bs = idx / WD;
  const int s = bs % SEQ;
  const int b = bs / SEQ;
  float v;
  if (s == 0) v = cls[w];
  else        v = tok[(size_t)(b*196 + s - 1) * WD + w];
  h[idx] = v + pe[(size_t)s * WD + w];
}

// ---------------------------------------------------------------------------
// LayerNorm: one block (256 thr) per row of 768
// ---------------------------------------------------------------------------
__global__ __launch_bounds__(256) void layernorm_k(
    const float* __restrict__ x, const float* __restrict__ g,
    const float* __restrict__ bb, float* __restrict__ y)
{
  const int row = blockIdx.x;
  const int tid = threadIdx.x;
  const float* xr = x + (size_t)row * WD;
  const float v0 = xr[tid], v1 = xr[tid+256], v2 = xr[tid+512];
  __shared__ float red[4];
  float s = v0 + v1 + v2;
  s = wave_sum(s);
  const int wv = tid >> 6, ln = tid & 63;
  if (ln == 0) red[wv] = s;
  __syncthreads();
  const float mean = (red[0]+red[1]+red[2]+red[3]) * (1.f/768.f);
  const float d0 = v0-mean, d1 = v1-mean, d2 = v2-mean;
  float sq = d0*d0 + d1*d1 + d2*d2;
  sq = wave_sum(sq);
  __syncthreads();
  if (ln == 0) red[wv] = sq;
  __syncthreads();
  const float var = (red[0]+red[1]+red[2]+red[3]) * (1.f/768.f);
  const float inv = rsqrtf(var + 1e-5f);
  float* yr = y + (size_t)row * WD;
  yr[tid]     = d0 * inv * g[tid]     + bb[tid];
  yr[tid+256] = d1 * inv * g[tid+256] + bb[tid+256];
  yr[tid+512] = d2 * inv * g[tid+512] + bb[tid+512];
}

// ---------------------------------------------------------------------------
// Fused QK^T * 1/8 + row softmax. Block: (qt -> 32 q rows) x (all 197 cols).
// Wave w owns rows qt*32 + w*8 .. +7; lane ln owns cols ln*4..+3 (ln<50 live).
// P stored zero-padded to att[bh][197][208].
// ---------------------------------------------------------------------------
__global__ __launch_bounds__(256) void attn_scores(
    const float* __restrict__ q, const float* __restrict__ kmat,
    float* __restrict__ att)
{
  __shared__ float QsT[64][36];    // [d][r]
  __shared__ float KsT[64][200];   // [d][t], cols 197..199 zero
  const int tid = threadIdx.x;
  const int qt = blockIdx.x;
  const int bh = blockIdx.y;
  const int b = bh / NH, hh = bh - b*NH;
  const size_t base = (size_t)b * SEQ * WD + (size_t)hh * HD;

  { // Q tile: lane map r = tid&31, d0 = (tid>>5)*8  (2-way bank on T-store)
    const int r  = tid & 31;
    const int d0 = (tid >> 5) * 8;
    const int grow = qt*32 + r;
    float4 v0 = {0,0,0,0}, v1 = {0,0,0,0};
    if (grow < SEQ) {
      const float* p = q + base + (size_t)grow * WD + d0;
      v0 = *(const float4*)p; v1 = *(const float4*)(p + 4);
    }
    QsT[d0+0][r] = v0.x; QsT[d0+1][r] = v0.y; QsT[d0+2][r] = v0.z; QsT[d0+3][r] = v0.w;
    QsT[d0+4][r] = v1.x; QsT[d0+5][r] = v1.y; QsT[d0+6][r] = v1.z; QsT[d0+7][r] = v1.w;
  }
  { // K tile (same mapping; 7 passes over t)
    const int tl = tid & 31;
    const int d0 = (tid >> 5) * 8;
    #pragma unroll
    for (int pass = 0; pass < 7; ++pass) {
      const int t = pass*32 + tl;
      if (t < 200) {
        float4 v0 = {0,0,0,0}, v1 = {0,0,0,0};
        if (t < SEQ) {
          const float* p = kmat + base + (size_t)t * WD + d0;
          v0 = *(const float4*)p; v1 = *(const float4*)(p + 4);
        }
        KsT[d0+0][t] = v0.x; KsT[d0+1][t] = v0.y; KsT[d0+2][t] = v0.z; KsT[d0+3][t] = v0.w;
        KsT[d0+4][t] = v1.x; KsT[d0+5][t] = v1.y; KsT[d0+6][t] = v1.z; KsT[d0+7][t] = v1.w;
      }
    }
  }
  __syncthreads();
  const int wv = tid >> 6;
  const int ln = tid & 63;
  const int ccol = (ln < 50) ? ln*4 : 0;
  float acc[8][4];
  #pragma unroll
  for (int i = 0; i < 8; ++i)
    #pragma unroll
    for (int j = 0; j < 4; ++j) acc[i][j] = 0.f;

  #pragma unroll 8
  for (int kx = 0; kx < 64; ++kx) {
    float a[8], bbv[4];
    *(float4*)&a[0]   = *(const float4*)&QsT[kx][wv*8];
    *(float4*)&a[4]   = *(const float4*)&QsT[kx][wv*8+4];
    *(float4*)&bbv[0] = *(const float4*)&KsT[kx][ccol];
    #pragma unroll
    for (int i = 0; i < 8; ++i)
      #pragma unroll
      for (int j = 0; j < 4; ++j)
        acc[i][j] = fmaf(a[i], bbv[j], acc[i][j]);
  }

  float* abase = att + (size_t)bh * SEQ * ATT_LD;
  #pragma unroll
  for (int i = 0; i < 8; ++i) {
    const int grow = qt*32 + wv*8 + i;
    float s[4];
    float mx = -1e30f;
    #pragma unroll
    for (int j = 0; j < 4; ++j) {
      const int t = ln*4 + j;
      s[j] = (t < SEQ) ? acc[i][j] * 0.125f : -1e30f;
      mx = fmaxf(mx, s[j]);
    }
    mx = wave_max(mx);
    float sum = 0.f;
    #pragma unroll
    for (int j = 0; j < 4; ++j) { s[j] = __expf(s[j] - mx); sum += s[j]; }
    sum = wave_sum(sum);
    const float inv = 1.f / sum;
    #pragma unroll
    for (int j = 0; j < 4; ++j) s[j] *= inv;
    if (grow < SEQ && ln < 52)
      *(float4*)(abase + (size_t)grow * ATT_LD + ln*4) = *(const float4*)s;
  }
}

// ---------------------------------------------------------------------------
// O = P @ V, batched per (b,h). 64-row tiles, K=208 (P zero-padded), N=64.
// ---------------------------------------------------------------------------
__global__ __launch_bounds__(256) void attn_pv(
    const float* __restrict__ att, const float* __restrict__ v,
    float* __restrict__ o)
{
  __shared__ float As[16][68];   // P^T tile [k][m]
  __shared__ float Bs[16][68];   // V tile  [k][n]
  const int tid = threadIdx.x;
  const int mt = blockIdx.x;
  const int bh = blockIdx.y;
  const int b = bh / NH, hh = bh - b*NH;
  const float* Abase = att + (size_t)bh * SEQ * ATT_LD;
  const size_t vbase = (size_t)b * SEQ * WD + (size_t)hh * HD;
  const int tx = tid & 15, ty = tid >> 4;
  const int ar = tid >> 2, ac = (tid & 3) * 4;
  const int br = tid >> 4, bc = (tid & 15) * 4;
  const int growA = mt*64 + ar;
  float acc[4][4] = {{0.f}};
  for (int k0 = 0; k0 < ATT_LD; k0 += 16) {
    float4 av = {0,0,0,0};
    if (growA < SEQ) av = *(const float4*)(Abase + (size_t)growA * ATT_LD + k0 + ac);
    const int t = k0 + br;
    float4 bv = {0,0,0,0};
    if (t < SEQ) bv = *(const float4*)(v + vbase + (size_t)t * WD + bc);
    __syncthreads();
    As[ac+0][ar] = av.x; As[ac+1][ar] = av.y; As[ac+2][ar] = av.z; As[ac+3][ar] = av.w;
    *(float4*)&Bs[br][bc] = bv;
    __syncthreads();
    #pragma unroll
    for (int kx = 0; kx < 16; ++kx) {
      const float4 a4 = *(const float4*)&As[kx][ty*4];
      const float4 b4 = *(const float4*)&Bs[kx][tx*4];
      const float aa[4]  = {a4.x, a4.y, a4.z, a4.w};
      const float bbv[4] = {b4.x, b4.y, b4.z, b4.w};
      #pragma unroll
      for (int i = 0; i < 4; ++i)
        #pragma unroll
        for (int j = 0; j < 4; ++j)
          acc[i][j] = fmaf(aa[i], bbv[j], acc[i][j]);
    }
  }
  #pragma unroll
  for (int i = 0; i < 4; ++i) {
    const int row = mt*64 + ty*4 + i;
    if (row < SEQ) {
      const float4 st = {acc[i][0], acc[i][1], acc[i][2], acc[i][3]};
      *(float4*)(o + (size_t)b * SEQ * WD + (size_t)row * WD + hh*HD + tx*4) = st;
    }
  }
}

// ---------------------------------------------------------------------------
// out[b] = normalize(h[b,0,:] @ proj)
// ---------------------------------------------------------------------------
__global__ __launch_bounds__(256) void head_k(
    const float* __restrict__ h, const float* __restrict__ proj,
    float* __restrict__ out)
{
  const int b = blockIdx.x;
  const int tid = threadIdx.x;
  __shared__ float hr[768];
  __shared__ float red[4];
  const float* hrow = h + (size_t)b * SEQ * WD;
  hr[tid] = hrow[tid]; hr[tid+256] = hrow[tid+256]; hr[tid+512] = hrow[tid+512];
  __syncthreads();
  float o0 = 0.f, o1 = 0.f;
  for (int kx = 0; kx < 768; ++kx) {
    const float hv = hr[kx];
    o0 = fmaf(hv, proj[(size_t)kx*512 + tid],       o0);
    o1 = fmaf(hv, proj[(size_t)kx*512 + tid + 256], o1);
  }
  float sq = o0*o0 + o1*o1;
  sq = wave_sum(sq);
  const int wv = tid >> 6, ln = tid & 63;
  if (ln == 0) red[wv] = sq;
  __syncthreads();
  const float inv = 1.f / sqrtf(red[0]+red[1]+red[2]+red[3]);
  out[(size_t)b*512 + tid]       = o0 * inv;
  out[(size_t)b*512 + tid + 256] = o1 * inv;
}

// ---------------------------------------------------------------------------
extern "C" void kernel_launch(void* const* d_in, const int* in_sizes, int n_in,
                              void* d_out, int out_size, void* d_ws, size_t ws_size,
                              hipStream_t stream) {
  const float* x      = (const float*)d_in[0];
  const float* conv_w = (const float*)d_in[1];
  const float* conv_b = (const float*)d_in[2];
  const float* cls    = (const float*)d_in[3];
  const float* pe     = (const float*)d_in[4];
  const float* ln1_g  = (const float*)d_in[5];
  const float* ln1_b  = (const float*)d_in[6];
  const float* wq = (const float*)d_in[7];  const float* bq = (const float*)d_in[8];
  const float* wk = (const float*)d_in[9];  const float* bk = (const float*)d_in[10];
  const float* wvw = (const float*)d_in[11]; const float* bv = (const float*)d_in[12];
  const float* wo = (const float*)d_in[13]; const float* bo = (const float*)d_in[14];
  const float* ln2_g = (const float*)d_in[15]; const float* ln2_b = (const float*)d_in[16];
  const float* w1 = (const float*)d_in[17]; const float* b1 = (const float*)d_in[18];
  const float* w2 = (const float*)d_in[19]; const float* b2 = (const float*)d_in[20];
  const float* proj = (const float*)d_in[21];
  float* out = (float*)d_out;

  float* ws = (float*)d_ws;
  const size_t TOK = (size_t)ROWS * WD;          // 4,841,472 floats
  float* h   = ws;
  float* y   = h  + TOK;
  float* qb  = y  + TOK;
  float* kb  = qb + TOK;
  float* vb  = kb + TOK;
  float* z   = vb + TOK;                          // 6304*3072; aliases im2col & att
  float* cT  = z + (size_t)ROWS * FF;             // 768*768
  float* im  = z;                                 // [6272][768]
  float* att = z;                                 // [384][197][208]
  float* ob  = qb;                                // attn output reuses q buffer

  // ---- patch embedding ----
  transpose_k<<<dim3(24,24), dim3(32,8), 0, stream>>>(conv_w, cT);
  im2col_k<<<dim3((PROWS*WD)/256), dim3(256), 0, stream>>>(x, im);
  gemm128<0><<<dim3(WD/128, PROWS/128), dim3(256), 0, stream>>>(
      im, cT, conv_b, nullptr, y, PROWS, WD, WD);
  assemble_k<<<dim3((ROWS*WD)/256), dim3(256), 0, stream>>>(y, cls, pe, h);

  const dim3 g768(WD/128, (ROWS+127)/128);   // 6 x 50
  const dim3 gff(FF/128, (ROWS+127)/128);    // 24 x 50

  for (int l = 0; l < NL; ++l) {
    const size_t wOff = (size_t)l * WD * WD;
    const size_t fOff = (size_t)l * WD * FF;
    const size_t vOff = (size_t)l * WD;
    const size_t fvOff = (size_t)l * FF;

    layernorm_k<<<dim3(ROWS), dim3(256), 0, stream>>>(h, ln1_g+vOff, ln1_b+vOff, y);
    gemm128<0><<<g768, dim3(256), 0, stream>>>(y, wq+wOff, bq+vOff, nullptr, qb, ROWS, WD, WD);
    gemm128<0><<<g768, dim3(256), 0, stream>>>(y, wk+wOff, bk+vOff, nullptr, kb, ROWS, WD, WD);
    gemm128<0><<<g768, dim3(256), 0, stream>>>(y, wvw+wOff, bv+vOff, nullptr, vb, ROWS, WD, WD);
    attn_scores<<<dim3(7, NB*NH), dim3(256), 0, stream>>>(qb, kb, att);
    attn_pv<<<dim3(4, NB*NH), dim3(256), 0, stream>>>(att, vb, ob);
    gemm128<1><<<g768, dim3(256), 0, stream>>>(ob, wo+wOff, bo+vOff, h, h, ROWS, WD, WD);
    layernorm_k<<<dim3(ROWS), dim3(256), 0, stream>>>(h, ln2_g+vOff, ln2_b+vOff, y);
    gemm128<2><<<gff, dim3(256), 0, stream>>>(y, w1+fOff, b1+fvOff, nullptr, z, ROWS, FF, WD);
    gemm128<1><<<g768, dim3(256), 0, stream>>>(z, w2+fOff, b2+vOff, h, h, ROWS, WD, FF);
  }

  head_k<<<dim3(NB), dim3(256), 0, stream>>>(h, proj, out);
}

// Round 2
// 5039.415 us; speedup vs baseline: 3.8644x; 3.8644x over previous
//
#include <hip/hip_runtime.h>
#include <math.h>

#define NB 32
#define SEQ 197
#define WD 768
#define NH 12
#define HD 64
#define FF 3072
#define NL 12
#define ROWS (NB*SEQ)      // 6304
#define MPAD 6400
#define PROWS (NB*196)     // 6272
#define ATT_LD 208

typedef __attribute__((ext_vector_type(8))) short short8x;   // 8 x bf16
typedef __attribute__((ext_vector_type(4))) float f32x4;

__device__ __forceinline__ ushort f2bf(float f) {
  unsigned u = __builtin_bit_cast(unsigned, f);
  u += 0x7fffu + ((u >> 16) & 1u);
  return (ushort)(u >> 16);
}

__device__ __forceinline__ void gload16(const ushort* g, ushort* l) {
  __builtin_amdgcn_global_load_lds(
      (const __attribute__((address_space(1))) void*)g,
      (__attribute__((address_space(3))) void*)l, 16, 0, 0);
}

__device__ __forceinline__ float wave_max(float v) {
  #pragma unroll
  for (int off = 32; off; off >>= 1) v = fmaxf(v, __shfl_xor(v, off));
  return v;
}
__device__ __forceinline__ float wave_sum(float v) {
  #pragma unroll
  for (int off = 32; off; off >>= 1) v += __shfl_xor(v, off);
  return v;
}

// ---------------------------------------------------------------------------
// bf16 MFMA GEMM (m97 structure): C[M,N] = epi(A[Mpad,K]bf16 @ Bt[N,K]bf16^T + bias)
// EPI 0: C fp32 = acc+bias.  1: C fp32 = acc+bias+R (in-place ok).
// EPI 2: Cb bf16 = gelu(acc+bias).
// 128x128 tile, BK=32, 4 waves, 4x4 frags of 16x16x32, global_load_lds(16B).
// ---------------------------------------------------------------------------
template<int EPI>
__global__ __launch_bounds__(256) void gemm_bt(
    const ushort* __restrict__ A, const ushort* __restrict__ Bt,
    const float* __restrict__ bias, const float* __restrict__ R,
    float* __restrict__ Cf, ushort* __restrict__ Cb,
    int M, int N, int K)
{
  __shared__ __align__(16) ushort As[128*32];
  __shared__ __align__(16) ushort Bs[128*32];
  const int tid = threadIdx.x;
  const int bm = blockIdx.y * 128, bn = blockIdx.x * 128;
  const int w = tid >> 6, ln = tid & 63;
  const int wr = (w >> 1) * 64, wc = (w & 1) * 64;
  // staging: thread t loads 16B; LDS linear [row][k] rows of 64B
  const int srow = tid >> 2, skoff = (tid & 3) * 8;
  const ushort* Ap = A + (size_t)(bm + srow) * K + skoff;
  const ushort* Bp = Bt + (size_t)(bn + srow) * K + skoff;
  ushort* AsW = As + w * 512;   // wave-uniform LDS base (1KB per wave)
  ushort* BsW = Bs + w * 512;
  const size_t half = (size_t)64 * K;
  const int fr = ln & 15, kg = ln >> 4;

  f32x4 acc[4][4];
  #pragma unroll
  for (int m = 0; m < 4; ++m)
    #pragma unroll
    for (int n = 0; n < 4; ++n) acc[m][n] = (f32x4){0.f, 0.f, 0.f, 0.f};

  for (int k0 = 0; k0 < K; k0 += 32) {
    __syncthreads();
    gload16(Ap + k0, AsW);
    gload16(Ap + half + k0, AsW + 2048);
    gload16(Bp + k0, BsW);
    gload16(Bp + half + k0, BsW + 2048);
    __syncthreads();
    short8x av[4], bv[4];
    #pragma unroll
    for (int m = 0; m < 4; ++m)
      av[m] = *(const short8x*)&As[(wr + m*16 + fr)*32 + kg*8];
    #pragma unroll
    for (int n = 0; n < 4; ++n)
      bv[n] = *(const short8x*)&Bs[(wc + n*16 + fr)*32 + kg*8];
    #pragma unroll
    for (int m = 0; m < 4; ++m)
      #pragma unroll
      for (int n = 0; n < 4; ++n)
        acc[m][n] = __builtin_amdgcn_mfma_f32_16x16x32_bf16(av[m], bv[n], acc[m][n], 0, 0, 0);
  }

  // C/D layout: col = lane&15, row = (lane>>4)*4 + reg   [m89-verified]
  const int crow = bm + wr + kg*4;
  const int ccol = bn + wc + fr;
  float bi[4];
  #pragma unroll
  for (int n = 0; n < 4; ++n) bi[n] = bias[ccol + n*16];
  #pragma unroll
  for (int m = 0; m < 4; ++m) {
    #pragma unroll
    for (int j = 0; j < 4; ++j) {
      const int r = crow + m*16 + j;
      if (r < M) {
        #pragma unroll
        for (int n = 0; n < 4; ++n) {
          const size_t off = (size_t)r * N + ccol + n*16;
          float vv = acc[m][n][j] + bi[n];
          if (EPI == 0) Cf[off] = vv;
          if (EPI == 1) Cf[off] = vv + R[off];
          if (EPI == 2) Cb[off] = f2bf(0.5f * vv * (1.f + erff(vv * 0.70710678118654752f)));
        }
      }
    }
  }
}

// ---------------------------------------------------------------------------
// transpose-cast: in [K][N] fp32 -> out [N][K] bf16
// ---------------------------------------------------------------------------
__global__ void tcast_k(const float* __restrict__ in, ushort* __restrict__ out,
                        int K, int N) {
  __shared__ float t[32][33];
  const int bx = blockIdx.x * 32, by = blockIdx.y * 32;
  const int tx = threadIdx.x, ty = threadIdx.y;
  #pragma unroll
  for (int j = 0; j < 32; j += 8)
    t[ty + j][tx] = in[(size_t)(by + ty + j) * N + bx + tx];
  __syncthreads();
  #pragma unroll
  for (int j = 0; j < 32; j += 8)
    out[(size_t)(bx + ty + j) * K + by + tx] = f2bf(t[tx][ty + j]);
}

// 4x [768][768] transpose-casts in one launch (z selects matrix)
__global__ void tcast4_k(const float* __restrict__ s0, const float* __restrict__ s1,
                         const float* __restrict__ s2, const float* __restrict__ s3,
                         ushort* __restrict__ d0, ushort* __restrict__ d1,
                         ushort* __restrict__ d2, ushort* __restrict__ d3) {
  const int z = blockIdx.z;
  const float* s = (z == 0) ? s0 : (z == 1) ? s1 : (z == 2) ? s2 : s3;
  ushort* d = (z == 0) ? d0 : (z == 1) ? d1 : (z == 2) ? d2 : d3;
  __shared__ float t[32][33];
  const int bx = blockIdx.x * 32, by = blockIdx.y * 32;
  const int tx = threadIdx.x, ty = threadIdx.y;
  #pragma unroll
  for (int j = 0; j < 32; j += 8)
    t[ty + j][tx] = s[(size_t)(by + ty + j) * WD + bx + tx];
  __syncthreads();
  #pragma unroll
  for (int j = 0; j < 32; j += 8)
    d[(size_t)(bx + ty + j) * WD + by + tx] = f2bf(t[tx][ty + j]);
}

// conv_w [768 out][768 k] is already [N][K] -> plain cast
__global__ void castcv_k(const float* __restrict__ in, ushort* __restrict__ out) {
  const int i = blockIdx.x * 256 + threadIdx.x;
  out[i] = f2bf(in[i]);
}

// ---------------------------------------------------------------------------
// im2col (stride = patch = 16 -> pure permutation), bf16 out
// ---------------------------------------------------------------------------
__global__ void im2col_k(const float* __restrict__ x, ushort* __restrict__ A) {
  const int idx = blockIdx.x * 256 + threadIdx.x;
  if (idx >= PROWS * WD) return;
  const int k = idx % WD;
  const int row = idx / WD;
  const int pw = k & 15, ph = (k >> 4) & 15, c = k >> 8;
  const int px = row % 14, py = (row / 14) % 14, b = row / 196;
  A[idx] = f2bf(x[(size_t)((b*3 + c)*224 + py*16 + ph) * 224 + px*16 + pw]);
}

// h[b,0,:] = cls + pe[0]; h[b,s,:] = tok[b,s-1,:] + pe[s]
__global__ void assemble_k(const float* __restrict__ tok, const float* __restrict__ cls,
                           const float* __restrict__ pe, float* __restrict__ h) {
  const int idx = blockIdx.x * 256 + threadIdx.x;
  if (idx >= ROWS * WD) return;
  const int w = idx % WD;
  const int bs = idx / WD;
  const int s = bs % SEQ;
  const int b = bs / SEQ;
  float v;
  if (s == 0) v = cls[w];
  else        v = tok[(size_t)(b*196 + s - 1) * WD + w];
  h[idx] = v + pe[(size_t)s * WD + w];
}

// ---------------------------------------------------------------------------
// LayerNorm fp32 in -> bf16 out. One block (256 thr) per row of 768.
// ---------------------------------------------------------------------------
__global__ __launch_bounds__(256) void layernorm_k(
    const float* __restrict__ x, const float* __restrict__ g,
    const float* __restrict__ bb, ushort* __restrict__ y)
{
  const int row = blockIdx.x;
  const int tid = threadIdx.x;
  const float* xr = x + (size_t)row * WD;
  const float v0 = xr[tid], v1 = xr[tid+256], v2 = xr[tid+512];
  __shared__ float red[4];
  float s = v0 + v1 + v2;
  s = wave_sum(s);
  const int wv = tid >> 6, ln = tid & 63;
  if (ln == 0) red[wv] = s;
  __syncthreads();
  const float mean = (red[0]+red[1]+red[2]+red[3]) * (1.f/768.f);
  const float d0 = v0-mean, d1 = v1-mean, d2 = v2-mean;
  float sq = d0*d0 + d1*d1 + d2*d2;
  sq = wave_sum(sq);
  __syncthreads();
  if (ln == 0) red[wv] = sq;
  __syncthreads();
  const float var = (red[0]+red[1]+red[2]+red[3]) * (1.f/768.f);
  const float inv = rsqrtf(var + 1e-5f);
  ushort* yr = y + (size_t)row * WD;
  yr[tid]     = f2bf(d0 * inv * g[tid]     + bb[tid]);
  yr[tid+256] = f2bf(d1 * inv * g[tid+256] + bb[tid+256]);
  yr[tid+512] = f2bf(d2 * inv * g[tid+512] + bb[tid+512]);
}

// ---------------------------------------------------------------------------
// Fused QK^T * 1/8 + row softmax (fp32, unchanged from R1).
// ---------------------------------------------------------------------------
__global__ __launch_bounds__(256) void attn_scores(
    const float* __restrict__ q, const float* __restrict__ kmat,
    float* __restrict__ att)
{
  __shared__ float QsT[64][36];
  __shared__ float KsT[64][200];
  const int tid = threadIdx.x;
  const int qt = blockIdx.x;
  const int bh = blockIdx.y;
  const int b = bh / NH, hh = bh - b*NH;
  const size_t base = (size_t)b * SEQ * WD + (size_t)hh * HD;

  {
    const int r  = tid & 31;
    const int d0 = (tid >> 5) * 8;
    const int grow = qt*32 + r;
    float4 v0 = {0,0,0,0}, v1 = {0,0,0,0};
    if (grow < SEQ) {
      const float* p = q + base + (size_t)grow * WD + d0;
      v0 = *(const float4*)p; v1 = *(const float4*)(p + 4);
    }
    QsT[d0+0][r] = v0.x; QsT[d0+1][r] = v0.y; QsT[d0+2][r] = v0.z; QsT[d0+3][r] = v0.w;
    QsT[d0+4][r] = v1.x; QsT[d0+5][r] = v1.y; QsT[d0+6][r] = v1.z; QsT[d0+7][r] = v1.w;
  }
  {
    const int tl = tid & 31;
    const int d0 = (tid >> 5) * 8;
    #pragma unroll
    for (int pass = 0; pass < 7; ++pass) {
      const int t = pass*32 + tl;
      if (t < 200) {
        float4 v0 = {0,0,0,0}, v1 = {0,0,0,0};
        if (t < SEQ) {
          const float* p = kmat + base + (size_t)t * WD + d0;
          v0 = *(const float4*)p; v1 = *(const float4*)(p + 4);
        }
        KsT[d0+0][t] = v0.x; KsT[d0+1][t] = v0.y; KsT[d0+2][t] = v0.z; KsT[d0+3][t] = v0.w;
        KsT[d0+4][t] = v1.x; KsT[d0+5][t] = v1.y; KsT[d0+6][t] = v1.z; KsT[d0+7][t] = v1.w;
      }
    }
  }
  __syncthreads();
  const int wv = tid >> 6;
  const int ln = tid & 63;
  const int ccol = (ln < 50) ? ln*4 : 0;
  float acc[8][4];
  #pragma unroll
  for (int i = 0; i < 8; ++i)
    #pragma unroll
    for (int j = 0; j < 4; ++j) acc[i][j] = 0.f;

  #pragma unroll 8
  for (int kx = 0; kx < 64; ++kx) {
    float a[8], bbv[4];
    *(float4*)&a[0]   = *(const float4*)&QsT[kx][wv*8];
    *(float4*)&a[4]   = *(const float4*)&QsT[kx][wv*8+4];
    *(float4*)&bbv[0] = *(const float4*)&KsT[kx][ccol];
    #pragma unroll
    for (int i = 0; i < 8; ++i)
      #pragma unroll
      for (int j = 0; j < 4; ++j)
        acc[i][j] = fmaf(a[i], bbv[j], acc[i][j]);
  }

  float* abase = att + (size_t)bh * SEQ * ATT_LD;
  #pragma unroll
  for (int i = 0; i < 8; ++i) {
    const int grow = qt*32 + wv*8 + i;
    float s[4];
    float mx = -1e30f;
    #pragma unroll
    for (int j = 0; j < 4; ++j) {
      const int t = ln*4 + j;
      s[j] = (t < SEQ) ? acc[i][j] * 0.125f : -1e30f;
      mx = fmaxf(mx, s[j]);
    }
    mx = wave_max(mx);
    float sum = 0.f;
    #pragma unroll
    for (int j = 0; j < 4; ++j) { s[j] = __expf(s[j] - mx); sum += s[j]; }
    sum = wave_sum(sum);
    const float inv = 1.f / sum;
    #pragma unroll
    for (int j = 0; j < 4; ++j) s[j] *= inv;
    if (grow < SEQ && ln < 52)
      *(float4*)(abase + (size_t)grow * ATT_LD + ln*4) = *(const float4*)s;
  }
}

// ---------------------------------------------------------------------------
// O = P @ V (fp32 math), bf16 out into obf.
// ---------------------------------------------------------------------------
__global__ __launch_bounds__(256) void attn_pv(
    const float* __restrict__ att, const float* __restrict__ v,
    ushort* __restrict__ obf)
{
  __shared__ float As2[16][68];
  __shared__ float Bs2[16][68];
  const int tid = threadIdx.x;
  const int mt = blockIdx.x;
  const int bh = blockIdx.y;
  const int b = bh / NH, hh = bh - b*NH;
  const float* Abase = att + (size_t)bh * SEQ * ATT_LD;
  const size_t vbase = (size_t)b * SEQ * WD + (size_t)hh * HD;
  const int tx = tid & 15, ty = tid >> 4;
  const int ar = tid >> 2, ac = (tid & 3) * 4;
  const int br = tid >> 4, bc = (tid & 15) * 4;
  const int growA = mt*64 + ar;
  float acc[4][4] = {{0.f}};
  for (int k0 = 0; k0 < ATT_LD; k0 += 16) {
    float4 av = {0,0,0,0};
    if (growA < SEQ) av = *(const float4*)(Abase + (size_t)growA * ATT_LD + k0 + ac);
    const int t = k0 + br;
    float4 bv = {0,0,0,0};
    if (t < SEQ) bv = *(const float4*)(v + vbase + (size_t)t * WD + bc);
    __syncthreads();
    As2[ac+0][ar] = av.x; As2[ac+1][ar] = av.y; As2[ac+2][ar] = av.z; As2[ac+3][ar] = av.w;
    *(float4*)&Bs2[br][bc] = bv;
    __syncthreads();
    #pragma unroll
    for (int kx = 0; kx < 16; ++kx) {
      const float4 a4 = *(const float4*)&As2[kx][ty*4];
      const float4 b4 = *(const float4*)&Bs2[kx][tx*4];
      const float aa[4]  = {a4.x, a4.y, a4.z, a4.w};
      const float bbv[4] = {b4.x, b4.y, b4.z, b4.w};
      #pragma unroll
      for (int i = 0; i < 4; ++i)
        #pragma unroll
        for (int j = 0; j < 4; ++j)
          acc[i][j] = fmaf(aa[i], bbv[j], acc[i][j]);
    }
  }
  #pragma unroll
  for (int i = 0; i < 4; ++i) {
    const int row = mt*64 + ty*4 + i;
    if (row < SEQ) {
      ushort4 st;
      st.x = f2bf(acc[i][0]); st.y = f2bf(acc[i][1]);
      st.z = f2bf(acc[i][2]); st.w = f2bf(acc[i][3]);
      *(ushort4*)(obf + (size_t)b * SEQ * WD + (size_t)row * WD + hh*HD + tx*4) = st;
    }
  }
}

// ---------------------------------------------------------------------------
// out[b] = normalize(h[b,0,:] @ proj)   (fp32, unchanged)
// ---------------------------------------------------------------------------
__global__ __launch_bounds__(256) void head_k(
    const float* __restrict__ h, const float* __restrict__ proj,
    float* __restrict__ out)
{
  const int b = blockIdx.x;
  const int tid = threadIdx.x;
  __shared__ float hr[768];
  __shared__ float red[4];
  const float* hrow = h + (size_t)b * SEQ * WD;
  hr[tid] = hrow[tid]; hr[tid+256] = hrow[tid+256]; hr[tid+512] = hrow[tid+512];
  __syncthreads();
  float o0 = 0.f, o1 = 0.f;
  for (int kx = 0; kx < 768; ++kx) {
    const float hv = hr[kx];
    o0 = fmaf(hv, proj[(size_t)kx*512 + tid],       o0);
    o1 = fmaf(hv, proj[(size_t)kx*512 + tid + 256], o1);
  }
  float sq = o0*o0 + o1*o1;
  sq = wave_sum(sq);
  const int wv = tid >> 6, ln = tid & 63;
  if (ln == 0) red[wv] = sq;
  __syncthreads();
  const float inv = 1.f / sqrtf(red[0]+red[1]+red[2]+red[3]);
  out[(size_t)b*512 + tid]       = o0 * inv;
  out[(size_t)b*512 + tid + 256] = o1 * inv;
}

// ---------------------------------------------------------------------------
extern "C" void kernel_launch(void* const* d_in, const int* in_sizes, int n_in,
                              void* d_out, int out_size, void* d_ws, size_t ws_size,
                              hipStream_t stream) {
  const float* x      = (const float*)d_in[0];
  const float* conv_w = (const float*)d_in[1];
  const float* conv_b = (const float*)d_in[2];
  const float* cls    = (const float*)d_in[3];
  const float* pe     = (const float*)d_in[4];
  const float* ln1_g  = (const float*)d_in[5];
  const float* ln1_b  = (const float*)d_in[6];
  const float* wq = (const float*)d_in[7];  const float* bq = (const float*)d_in[8];
  const float* wk = (const float*)d_in[9];  const float* bk = (const float*)d_in[10];
  const float* wvw = (const float*)d_in[11]; const float* bv = (const float*)d_in[12];
  const float* wo = (const float*)d_in[13]; const float* bo = (const float*)d_in[14];
  const float* ln2_g = (const float*)d_in[15]; const float* ln2_b = (const float*)d_in[16];
  const float* w1 = (const float*)d_in[17]; const float* b1 = (const float*)d_in[18];
  const float* w2 = (const float*)d_in[19]; const float* b2 = (const float*)d_in[20];
  const float* proj = (const float*)d_in[21];
  float* out = (float*)d_out;

  float* ws = (float*)d_ws;
  const size_t TOK = (size_t)ROWS * WD;          // 4,841,472 floats
  float* h  = ws;
  float* q  = h + TOK;
  float* k  = q + TOK;
  float* v  = k + TOK;
  float* un = v + TOK;                           // union region: 15,733,760 floats
  float*  att  = un;                             // [384][197][208] fp32
  ushort* zbf  = (ushort*)un;                    // [6400][3072] bf16
  ushort* imbf = (ushort*)un;                    // [6272][768] bf16
  float* after = un + (size_t)384 * SEQ * ATT_LD;
  ushort* ybf  = (ushort*)after;                 // [6400][768] bf16
  ushort* wtbf = (ushort*)(after + (size_t)MPAD * WD / 2);  // 7,077,888 bf16
  ushort* wt_q = wtbf;
  ushort* wt_k = wtbf + 589824;
  ushort* wt_v = wtbf + 2*589824;
  ushort* wt_o = wtbf + 3*589824;
  ushort* wt_1 = wtbf + 4*589824;
  ushort* wt_2 = wt_1 + 2359296;
  ushort* cbf  = wtbf;                           // conv weights (pre-loop only)

  // ---- patch embedding ----
  castcv_k<<<dim3(2304), dim3(256), 0, stream>>>(conv_w, cbf);
  im2col_k<<<dim3((PROWS*WD)/256), dim3(256), 0, stream>>>(x, imbf);
  gemm_bt<0><<<dim3(6, 49), dim3(256), 0, stream>>>(
      imbf, cbf, conv_b, nullptr, q, nullptr, PROWS, WD, WD);
  assemble_k<<<dim3((ROWS*WD)/256), dim3(256), 0, stream>>>(q, cls, pe, h);

  const dim3 g768(6, 50);
  const dim3 gff(24, 50);
  const dim3 tdim(32, 8);

  for (int l = 0; l < NL; ++l) {
    const size_t wOff = (size_t)l * WD * WD;
    const size_t fOff = (size_t)l * WD * FF;
    const size_t vOff = (size_t)l * WD;
    const size_t fvOff = (size_t)l * FF;

    tcast4_k<<<dim3(24,24,4), tdim, 0, stream>>>(wq+wOff, wk+wOff, wvw+wOff, wo+wOff,
                                                 wt_q, wt_k, wt_v, wt_o);
    tcast_k<<<dim3(96,24), tdim, 0, stream>>>(w1+fOff, wt_1, WD, FF);
    tcast_k<<<dim3(24,96), tdim, 0, stream>>>(w2+fOff, wt_2, FF, WD);

    layernorm_k<<<dim3(ROWS), dim3(256), 0, stream>>>(h, ln1_g+vOff, ln1_b+vOff, ybf);
    gemm_bt<0><<<g768, dim3(256), 0, stream>>>(ybf, wt_q, bq+vOff, nullptr, q, nullptr, ROWS, WD, WD);
    gemm_bt<0><<<g768, dim3(256), 0, stream>>>(ybf, wt_k, bk+vOff, nullptr, k, nullptr, ROWS, WD, WD);
    gemm_bt<0><<<g768, dim3(256), 0, stream>>>(ybf, wt_v, bv+vOff, nullptr, v, nullptr, ROWS, WD, WD);
    attn_scores<<<dim3(7, NB*NH), dim3(256), 0, stream>>>(q, k, att);
    attn_pv<<<dim3(4, NB*NH), dim3(256), 0, stream>>>(att, v, ybf);
    gemm_bt<1><<<g768, dim3(256), 0, stream>>>(ybf, wt_o, bo+vOff, h, h, nullptr, ROWS, WD, WD);
    layernorm_k<<<dim3(ROWS), dim3(256), 0, stream>>>(h, ln2_g+vOff, ln2_b+vOff, ybf);
    gemm_bt<2><<<gff, dim3(256), 0, stream>>>(ybf, wt_1, b1+fvOff, nullptr, nullptr, zbf, ROWS, FF, WD);
    gemm_bt<1><<<g768, dim3(256), 0, stream>>>(zbf, wt_2, b2+vOff, h, h, nullptr, ROWS, WD, FF);
  }

  head_k<<<dim3(NB), dim3(256), 0, stream>>>(h, proj, out);
}

// Round 4
// 3540.145 us; speedup vs baseline: 5.5010x; 1.4235x over previous
//
#include <hip/hip_runtime.h>
#include <math.h>

#define NB 32
#define SEQ 197
#define WD 768
#define NH 12
#define HD 64
#define FF 3072
#define NL 12
#define ROWS (NB*SEQ)      // 6304
#define MPAD 6400
#define PROWS (NB*196)     // 6272

typedef __attribute__((ext_vector_type(8))) short short8x;   // 8 x bf16
typedef __attribute__((ext_vector_type(4))) float f32x4;

__device__ __forceinline__ ushort f2bf(float f) {
  unsigned u = __builtin_bit_cast(unsigned, f);
  u += 0x7fffu + ((u >> 16) & 1u);
  return (ushort)(u >> 16);
}

__device__ __forceinline__ void gload16(const ushort* g, ushort* l) {
  __builtin_amdgcn_global_load_lds(
      (const __attribute__((address_space(1))) void*)g,
      (__attribute__((address_space(3))) void*)l, 16, 0, 0);
}

__device__ __forceinline__ float wave_sum(float v) {
  #pragma unroll
  for (int off = 32; off; off >>= 1) v += __shfl_xor(v, off);
  return v;
}

// ---------------------------------------------------------------------------
// bf16 MFMA GEMM (m97 structure + m204 XCD swizzle):
//   C[M,N] = epi(A[Mpad,K]bf16 @ Bt[N,K]bf16^T + bias)
// EPI 0: Cf fp32. 1: Cf fp32 += R. 2: Cb bf16 = gelu. 3: Cb bf16 linear.
// ---------------------------------------------------------------------------
template<int EPI>
__global__ __launch_bounds__(256) void gemm_bt(
    const ushort* __restrict__ A, const ushort* __restrict__ Bt,
    const float* __restrict__ bias, const float* __restrict__ R,
    float* __restrict__ Cf, ushort* __restrict__ Cb,
    int M, int N, int K)
{
  __shared__ __align__(16) ushort As[128*32];
  __shared__ __align__(16) ushort Bs[128*32];
  const int tid = threadIdx.x;
  // bijective XCD swizzle: contiguous tile-ids (sharing A row-panels) per XCD
  const int gx = gridDim.x;
  const int nwg = gx * gridDim.y;
  const int orig = blockIdx.y * gx + blockIdx.x;
  const int xcd = orig & 7, lin = orig >> 3;
  const int qq = nwg >> 3, rr = nwg & 7;
  const int id = xcd*qq + (xcd < rr ? xcd : rr) + lin;
  const int bm = (id / gx) * 128;
  const int bn = (id % gx) * 128;

  const int w = tid >> 6, ln = tid & 63;
  const int wr = (w >> 1) * 64, wc = (w & 1) * 64;
  const int srow = tid >> 2, skoff = (tid & 3) * 8;
  const ushort* Ap = A + (size_t)(bm + srow) * K + skoff;
  const ushort* Bp = Bt + (size_t)(bn + srow) * K + skoff;
  ushort* AsW = As + w * 512;
  ushort* BsW = Bs + w * 512;
  const size_t half = (size_t)64 * K;
  const int fr = ln & 15, kg = ln >> 4;

  f32x4 acc[4][4];
  #pragma unroll
  for (int m = 0; m < 4; ++m)
    #pragma unroll
    for (int n = 0; n < 4; ++n) acc[m][n] = (f32x4){0.f, 0.f, 0.f, 0.f};

  for (int k0 = 0; k0 < K; k0 += 32) {
    __syncthreads();
    gload16(Ap + k0, AsW);
    gload16(Ap + half + k0, AsW + 2048);
    gload16(Bp + k0, BsW);
    gload16(Bp + half + k0, BsW + 2048);
    __syncthreads();
    short8x av[4], bv[4];
    #pragma unroll
    for (int m = 0; m < 4; ++m)
      av[m] = *(const short8x*)&As[(wr + m*16 + fr)*32 + kg*8];
    #pragma unroll
    for (int n = 0; n < 4; ++n)
      bv[n] = *(const short8x*)&Bs[(wc + n*16 + fr)*32 + kg*8];
    #pragma unroll
    for (int m = 0; m < 4; ++m)
      #pragma unroll
      for (int n = 0; n < 4; ++n)
        acc[m][n] = __builtin_amdgcn_mfma_f32_16x16x32_bf16(av[m], bv[n], acc[m][n], 0, 0, 0);
  }

  const int crow = bm + wr + kg*4;
  const int ccol = bn + wc + fr;
  float bi[4];
  #pragma unroll
  for (int n = 0; n < 4; ++n) bi[n] = bias[ccol + n*16];
  #pragma unroll
  for (int m = 0; m < 4; ++m) {
    #pragma unroll
    for (int j = 0; j < 4; ++j) {
      const int r = crow + m*16 + j;
      if (r < M) {
        #pragma unroll
        for (int n = 0; n < 4; ++n) {
          const size_t off = (size_t)r * N + ccol + n*16;
          float vv = acc[m][n][j] + bi[n];
          if (EPI == 0) Cf[off] = vv;
          if (EPI == 1) Cf[off] = vv + R[off];
          if (EPI == 2) Cb[off] = f2bf(0.5f * vv * (1.f + erff(vv * 0.70710678118654752f)));
          if (EPI == 3) Cb[off] = f2bf(vv);
        }
      }
    }
  }
}

// ---------------------------------------------------------------------------
// Fused attention: one block = 64 q-rows (4 waves x 16) for one (b,h).
// K padded [208][72] and V^T [64][232] fully in LDS; P overlays K region.
// ---------------------------------------------------------------------------
__global__ __launch_bounds__(256) void attn_fused(
    const ushort* __restrict__ qkv,   // [6400][2304] : Q | K | V
    ushort* __restrict__ obf)         // [6400][768]
{
  __shared__ __align__(16) ushort KP[208*72];   // K, later P (4 x [16][232])
  __shared__ __align__(16) ushort Vt[64*232];
  const int tid = threadIdx.x;
  const int w = tid >> 6, l = tid & 63;
  const int fr = l & 15, kg = l >> 4;
  // swizzle 1536 blocks over XCDs (keeps one bh's 4 q-tiles together)
  const int orig = blockIdx.y * 4 + blockIdx.x;
  const int id = (orig & 7) * 192 + (orig >> 3);
  const int qt = id & 3;
  const int bh = id >> 2;
  const int b = bh / 12, hh = bh - b*12;
  const size_t qrow0 = (size_t)b * SEQ;
  const ushort* kbase = qkv + qrow0*2304 + 768 + hh*64;
  const ushort* vbase = qkv + qrow0*2304 + 1536 + hh*64;

  #pragma unroll
  for (int it = 0; it < 7; ++it) {             // K: 208 rows x 64, zero-padded
    const int idx = it*256 + tid;
    if (idx < 1664) {
      const int row = idx >> 3, kc = (idx & 7) << 3;
      short8x v = (short8x){0,0,0,0,0,0,0,0};
      if (row < SEQ) v = *(const short8x*)(kbase + (size_t)row*2304 + kc);
      *(short8x*)&KP[row*72 + kc] = v;
    }
  }
  #pragma unroll
  for (int it = 0; it < 7; ++it) {             // V^T: 64 x 224, zero-padded
    const int t = it*32 + (tid & 31);
    const int dc = ((tid >> 5) & 7) << 3;
    short8x v = (short8x){0,0,0,0,0,0,0,0};
    if (t < SEQ) v = *(const short8x*)(vbase + (size_t)t*2304 + dc);
    #pragma unroll
    for (int j = 0; j < 8; ++j) Vt[(dc + j)*232 + t] = (ushort)v[j];
  }
  const int s_l = qt*64 + w*16 + fr;
  const ushort* qbase = qkv + (qrow0 + (s_l < SEQ ? s_l : SEQ-1))*2304 + hh*64;
  const short8x qf0 = *(const short8x*)(qbase + kg*8);
  const short8x qf1 = *(const short8x*)(qbase + 32 + kg*8);
  __syncthreads();

  // S = (Q K^T): 13 t-fragments of 16
  f32x4 sacc[13];
  #pragma unroll
  for (int f = 0; f < 13; ++f) sacc[f] = (f32x4){0.f,0.f,0.f,0.f};
  #pragma unroll
  for (int f = 0; f < 13; ++f) {
    const short8x kf0 = *(const short8x*)&KP[(f*16 + fr)*72 + kg*8];
    const short8x kf1 = *(const short8x*)&KP[(f*16 + fr)*72 + 32 + kg*8];
    sacc[f] = __builtin_amdgcn_mfma_f32_16x16x32_bf16(qf0, kf0, sacc[f], 0, 0, 0);
    sacc[f] = __builtin_amdgcn_mfma_f32_16x16x32_bf16(qf1, kf1, sacc[f], 0, 0, 0);
  }
  // softmax: rows = (kg*4 + j), cols distributed over fr (16 lanes)
  float mx[4] = {-1e30f,-1e30f,-1e30f,-1e30f};
  #pragma unroll
  for (int f = 0; f < 13; ++f)
    #pragma unroll
    for (int j = 0; j < 4; ++j) {
      float v = sacc[f][j] * 0.125f;
      if (f == 12 && fr >= 5) v = -1e30f;      // t >= 197 masked
      sacc[f][j] = v;
      mx[j] = fmaxf(mx[j], v);
    }
  #pragma unroll
  for (int j = 0; j < 4; ++j) {
    mx[j] = fmaxf(mx[j], __shfl_xor(mx[j], 1));
    mx[j] = fmaxf(mx[j], __shfl_xor(mx[j], 2));
    mx[j] = fmaxf(mx[j], __shfl_xor(mx[j], 4));
    mx[j] = fmaxf(mx[j], __shfl_xor(mx[j], 8));
  }
  float sm[4] = {0.f,0.f,0.f,0.f};
  #pragma unroll
  for (int f = 0; f < 13; ++f)
    #pragma unroll
    for (int j = 0; j < 4; ++j) {
      const float e = __expf(sacc[f][j] - mx[j]);
      sacc[f][j] = e; sm[j] += e;
    }
  #pragma unroll
  for (int j = 0; j < 4; ++j) {
    sm[j] += __shfl_xor(sm[j], 1);
    sm[j] += __shfl_xor(sm[j], 2);
    sm[j] += __shfl_xor(sm[j], 4);
    sm[j] += __shfl_xor(sm[j], 8);
    sm[j] = 1.f / sm[j];
  }
  __syncthreads();                              // everyone done reading K
  ushort* P = &KP[w*16*232];                    // per-wave P tile [16][232]
  #pragma unroll
  for (int f = 0; f < 13; ++f)
    #pragma unroll
    for (int j = 0; j < 4; ++j)
      P[(kg*4 + j)*232 + f*16 + fr] = f2bf(sacc[f][j] * sm[j]);
  #pragma unroll
  for (int j = 0; j < 4; ++j)
    P[(kg*4 + j)*232 + 208 + fr] = 0;           // zero pad t 208..223
  __syncthreads();

  // O = P V : P as A-frags, V^T rows as B-frags
  short8x pf[7];
  #pragma unroll
  for (int tc = 0; tc < 7; ++tc)
    pf[tc] = *(const short8x*)&P[fr*232 + tc*32 + kg*8];
  f32x4 oacc[4];
  #pragma unroll
  for (int df = 0; df < 4; ++df) oacc[df] = (f32x4){0.f,0.f,0.f,0.f};
  #pragma unroll
  for (int df = 0; df < 4; ++df)
    #pragma unroll
    for (int tc = 0; tc < 7; ++tc) {
      const short8x vf = *(const short8x*)&Vt[(df*16 + fr)*232 + tc*32 + kg*8];
      oacc[df] = __builtin_amdgcn_mfma_f32_16x16x32_bf16(pf[tc], vf, oacc[df], 0, 0, 0);
    }
  #pragma unroll
  for (int df = 0; df < 4; ++df)
    #pragma unroll
    for (int j = 0; j < 4; ++j) {
      const int s = qt*64 + w*16 + kg*4 + j;
      if (s < SEQ)
        obf[(qrow0 + s)*768 + hh*64 + df*16 + fr] = f2bf(oacc[df][j]);
    }
}

// ---------------------------------------------------------------------------
__global__ void tcast_k(const float* __restrict__ in, ushort* __restrict__ out,
                        int K, int N) {
  __shared__ float t[32][33];
  const int bx = blockIdx.x * 32, by = blockIdx.y * 32;
  const int tx = threadIdx.x, ty = threadIdx.y;
  #pragma unroll
  for (int j = 0; j < 32; j += 8)
    t[ty + j][tx] = in[(size_t)(by + ty + j) * N + bx + tx];
  __syncthreads();
  #pragma unroll
  for (int j = 0; j < 32; j += 8)
    out[(size_t)(bx + ty + j) * K + by + tx] = f2bf(t[tx][ty + j]);
}

__global__ void tcast4_k(const float* __restrict__ s0, const float* __restrict__ s1,
                         const float* __restrict__ s2, const float* __restrict__ s3,
                         ushort* __restrict__ d0, ushort* __restrict__ d1,
                         ushort* __restrict__ d2, ushort* __restrict__ d3) {
  const int z = blockIdx.z;
  const float* s = (z == 0) ? s0 : (z == 1) ? s1 : (z == 2) ? s2 : s3;
  ushort* d = (z == 0) ? d0 : (z == 1) ? d1 : (z == 2) ? d2 : d3;
  __shared__ float t[32][33];
  const int bx = blockIdx.x * 32, by = blockIdx.y * 32;
  const int tx = threadIdx.x, ty = threadIdx.y;
  #pragma unroll
  for (int j = 0; j < 32; j += 8)
    t[ty + j][tx] = s[(size_t)(by + ty + j) * WD + bx + tx];
  __syncthreads();
  #pragma unroll
  for (int j = 0; j < 32; j += 8)
    d[(size_t)(bx + ty + j) * WD + by + tx] = f2bf(t[tx][ty + j]);
}

__global__ void castcv_k(const float* __restrict__ in, ushort* __restrict__ out) {
  const int i = blockIdx.x * 256 + threadIdx.x;
  out[i] = f2bf(in[i]);
}

__global__ void bcat_k(const float* __restrict__ a, const float* __restrict__ b,
                       const float* __restrict__ c, float* __restrict__ d) {
  const int i = blockIdx.x * 256 + threadIdx.x;
  if (i < 2304) d[i] = (i < 768) ? a[i] : (i < 1536) ? b[i - 768] : c[i - 1536];
}

__global__ void im2col_k(const float* __restrict__ x, ushort* __restrict__ A) {
  const int idx = blockIdx.x * 256 + threadIdx.x;
  if (idx >= PROWS * WD) return;
  const int k = idx % WD;
  const int row = idx / WD;
  const int pw = k & 15, ph = (k >> 4) & 15, c = k >> 8;
  const int px = row % 14, py = (row / 14) % 14, b = row / 196;
  A[idx] = f2bf(x[(size_t)((b*3 + c)*224 + py*16 + ph) * 224 + px*16 + pw]);
}

__global__ void assemble_k(const float* __restrict__ tok, const float* __restrict__ cls,
                           const float* __restrict__ pe, float* __restrict__ h) {
  const int idx = blockIdx.x * 256 + threadIdx.x;
  if (idx >= ROWS * WD) return;
  const int w = idx % WD;
  const int bs = idx / WD;
  const int s = bs % SEQ;
  const int b = bs / SEQ;
  float v;
  if (s == 0) v = cls[w];
  else        v = tok[(size_t)(b*196 + s - 1) * WD + w];
  h[idx] = v + pe[(size_t)s * WD + w];
}

__global__ __launch_bounds__(256) void layernorm_k(
    const float* __restrict__ x, const float* __restrict__ g,
    const float* __restrict__ bb, ushort* __restrict__ y)
{
  const int row = blockIdx.x;
  const int tid = threadIdx.x;
  const float* xr = x + (size_t)row * WD;
  const float v0 = xr[tid], v1 = xr[tid+256], v2 = xr[tid+512];
  __shared__ float red[4];
  float s = v0 + v1 + v2;
  s = wave_sum(s);
  const int wv = tid >> 6, ln = tid & 63;
  if (ln == 0) red[wv] = s;
  __syncthreads();
  const float mean = (red[0]+red[1]+red[2]+red[3]) * (1.f/768.f);
  const float d0 = v0-mean, d1 = v1-mean, d2 = v2-mean;
  float sq = d0*d0 + d1*d1 + d2*d2;
  sq = wave_sum(sq);
  __syncthreads();
  if (ln == 0) red[wv] = sq;
  __syncthreads();
  const float var = (red[0]+red[1]+red[2]+red[3]) * (1.f/768.f);
  const float inv = rsqrtf(var + 1e-5f);
  ushort* yr = y + (size_t)row * WD;
  yr[tid]     = f2bf(d0 * inv * g[tid]     + bb[tid]);
  yr[tid+256] = f2bf(d1 * inv * g[tid+256] + bb[tid+256]);
  yr[tid+512] = f2bf(d2 * inv * g[tid+512] + bb[tid+512]);
}

__global__ __launch_bounds__(256) void head_k(
    const float* __restrict__ h, const float* __restrict__ proj,
    float* __restrict__ out)
{
  const int b = blockIdx.x;
  const int tid = threadIdx.x;
  __shared__ float hr[768];
  __shared__ float red[4];
  const float* hrow = h + (size_t)b * SEQ * WD;
  hr[tid] = hrow[tid]; hr[tid+256] = hrow[tid+256]; hr[tid+512] = hrow[tid+512];
  __syncthreads();
  float o0 = 0.f, o1 = 0.f;
  for (int kx = 0; kx < 768; ++kx) {
    const float hv = hr[kx];
    o0 = fmaf(hv, proj[(size_t)kx*512 + tid],       o0);
    o1 = fmaf(hv, proj[(size_t)kx*512 + tid + 256], o1);
  }
  float sq = o0*o0 + o1*o1;
  sq = wave_sum(sq);
  const int wv = tid >> 6, ln = tid & 63;
  if (ln == 0) red[wv] = sq;
  __syncthreads();
  const float inv = 1.f / sqrtf(red[0]+red[1]+red[2]+red[3]);
  out[(size_t)b*512 + tid]       = o0 * inv;
  out[(size_t)b*512 + tid + 256] = o1 * inv;
}

// ---------------------------------------------------------------------------
extern "C" void kernel_launch(void* const* d_in, const int* in_sizes, int n_in,
                              void* d_out, int out_size, void* d_ws, size_t ws_size,
                              hipStream_t stream) {
  const float* x      = (const float*)d_in[0];
  const float* conv_w = (const float*)d_in[1];
  const float* conv_b = (const float*)d_in[2];
  const float* cls    = (const float*)d_in[3];
  const float* pe     = (const float*)d_in[4];
  const float* ln1_g  = (const float*)d_in[5];
  const float* ln1_b  = (const float*)d_in[6];
  const float* wq = (const float*)d_in[7];  const float* bq = (const float*)d_in[8];
  const float* wk = (const float*)d_in[9];  const float* bk = (const float*)d_in[10];
  const float* wvw = (const float*)d_in[11]; const float* bv = (const float*)d_in[12];
  const float* wo = (const float*)d_in[13]; const float* bo = (const float*)d_in[14];
  const float* ln2_g = (const float*)d_in[15]; const float* ln2_b = (const float*)d_in[16];
  const float* w1 = (const float*)d_in[17]; const float* b1 = (const float*)d_in[18];
  const float* w2 = (const float*)d_in[19]; const float* b2 = (const float*)d_in[20];
  const float* proj = (const float*)d_in[21];
  float* out = (float*)d_out;

  float* ws = (float*)d_ws;
  const size_t TOK = (size_t)ROWS * WD;          // 4,841,472 floats
  float* h = ws;
  ushort* ub = (ushort*)(ws + TOK);
  ushort* ybf    = ub;  ub += (size_t)MPAD * WD;        // [6400][768]
  ushort* qkv    = ub;  ub += (size_t)MPAD * 2304;      // [6400][2304]
  ushort* obf    = ub;  ub += (size_t)MPAD * WD;        // [6400][768]
  ushort* zbf    = ub;  ub += (size_t)MPAD * FF;        // [6400][3072]
  ushort* wt_qkv = ub;  ub += (size_t)2304 * WD;
  ushort* wt_o   = ub;  ub += (size_t)WD * WD;
  ushort* wt_1   = ub;  ub += (size_t)WD * FF;
  ushort* wt_2   = ub;  ub += (size_t)FF * WD;
  float* bqkv = (float*)ub;  ub += 4608;
  // patch-embed scratch overlays zbf: imbf [6272][768] bf16, then ypatch fp32
  ushort* imbf   = zbf;
  float*  ypatch = (float*)(zbf + (size_t)PROWS * WD);
  ushort* cbf    = wt_qkv;   // conv weights, pre-loop only

  // ---- patch embedding ----
  castcv_k<<<dim3(2304), dim3(256), 0, stream>>>(conv_w, cbf);
  im2col_k<<<dim3((PROWS*WD)/256), dim3(256), 0, stream>>>(x, imbf);
  gemm_bt<0><<<dim3(6, 49), dim3(256), 0, stream>>>(
      imbf, cbf, conv_b, nullptr, ypatch, nullptr, PROWS, WD, WD);
  assemble_k<<<dim3((ROWS*WD)/256), dim3(256), 0, stream>>>(ypatch, cls, pe, h);

  const dim3 gqkv(18, 50);
  const dim3 g768(6, 50);
  const dim3 gff(24, 50);
  const dim3 gattn(4, NB*NH);
  const dim3 tdim(32, 8);

  for (int l = 0; l < NL; ++l) {
    const size_t wOff = (size_t)l * WD * WD;
    const size_t fOff = (size_t)l * WD * FF;
    const size_t vOff = (size_t)l * WD;
    const size_t fvOff = (size_t)l * FF;

    tcast4_k<<<dim3(24,24,4), tdim, 0, stream>>>(
        wq+wOff, wk+wOff, wvw+wOff, wo+wOff,
        wt_qkv, wt_qkv + 589824, wt_qkv + 1179648, wt_o);
    tcast_k<<<dim3(96,24), tdim, 0, stream>>>(w1+fOff, wt_1, WD, FF);
    tcast_k<<<dim3(24,96), tdim, 0, stream>>>(w2+fOff, wt_2, FF, WD);
    bcat_k<<<dim3(9), dim3(256), 0, stream>>>(bq+vOff, bk+vOff, bv+vOff, bqkv);

    layernorm_k<<<dim3(ROWS), dim3(256), 0, stream>>>(h, ln1_g+vOff, ln1_b+vOff, ybf);
    gemm_bt<3><<<gqkv, dim3(256), 0, stream>>>(ybf, wt_qkv, bqkv, nullptr,
                                               nullptr, qkv, ROWS, 2304, WD);
    attn_fused<<<gattn, dim3(256), 0, stream>>>(qkv, obf);
    gemm_bt<1><<<g768, dim3(256), 0, stream>>>(obf, wt_o, bo+vOff, h, h, nullptr, ROWS, WD, WD);
    layernorm_k<<<dim3(ROWS), dim3(256), 0, stream>>>(h, ln2_g+vOff, ln2_b+vOff, ybf);
    gemm_bt<2><<<gff, dim3(256), 0, stream>>>(ybf, wt_1, b1+fvOff, nullptr,
                                              nullptr, zbf, ROWS, FF, WD);
    gemm_bt<1><<<g768, dim3(256), 0, stream>>>(zbf, wt_2, b2+vOff, h, h, nullptr, ROWS, WD, FF);
  }

  head_k<<<dim3(NB), dim3(256), 0, stream>>>(h, proj, out);
}

// Round 8
// 3317.542 us; speedup vs baseline: 5.8702x; 1.0671x over previous
//
#include <hip/hip_runtime.h>
#include <math.h>

#define NB 32
#define SEQ 197
#define WD 768
#define NH 12
#define HD 64
#define FF 3072
#define NL 12
#define ROWS (NB*SEQ)      // 6304
#define MPAD 6400
#define PROWS (NB*196)     // 6272

typedef __attribute__((ext_vector_type(8))) short short8x;   // 8 x bf16
typedef __attribute__((ext_vector_type(4))) float f32x4;

__device__ __forceinline__ ushort f2bf(float f) {
  unsigned u = __builtin_bit_cast(unsigned, f);
  u += 0x7fffu + ((u >> 16) & 1u);
  return (ushort)(u >> 16);
}

__device__ __forceinline__ void gload16(const ushort* g, ushort* l) {
  __builtin_amdgcn_global_load_lds(
      (const __attribute__((address_space(1))) void*)g,
      (__attribute__((address_space(3))) void*)l, 16, 0, 0);
}

__device__ __forceinline__ float wave_sum(float v) {
  #pragma unroll
  for (int off = 32; off; off >>= 1) v += __shfl_xor(v, off);
  return v;
}

// ---------------------------------------------------------------------------
// bf16 MFMA GEMM, 2-phase double-buffered (T3-minimum), 128x128, BK=32.
//   C[M,N] = epi(A[Mpad,K]bf16 @ Bt[N,K]bf16^T + bias)
// EPI 0: Cf fp32. 1: Cf fp32 += R. 2: Cb bf16 gelu. 3: Cb bf16 linear.
// EPI 4: split-K partial, no bias: Cf(+z*MPAD*N)[off] = acc  (K chunk z).
// ---------------------------------------------------------------------------
template<int EPI>
__global__ __launch_bounds__(256) void gemm_bt(
    const ushort* __restrict__ A, const ushort* __restrict__ Bt,
    const float* __restrict__ bias, const float* __restrict__ R,
    float* __restrict__ Cf, ushort* __restrict__ Cb,
    int M, int N, int K, int kspl)
{
  __shared__ __align__(16) ushort As[2][128*32];
  __shared__ __align__(16) ushort Bs[2][128*32];
  const int tid = threadIdx.x;
  // bijective XCD swizzle over the (x,y) grid
  const int gx = gridDim.x;
  const int nwg = gx * gridDim.y;
  const int orig = blockIdx.y * gx + blockIdx.x;
  const int xcd = orig & 7, lin = orig >> 3;
  const int qq = nwg >> 3, rr = nwg & 7;
  const int id = xcd*qq + (xcd < rr ? xcd : rr) + lin;
  const int bm = (id / gx) * 128;
  const int bn = (id % gx) * 128;
  const int koff = blockIdx.z * kspl;

  const int w = tid >> 6, ln = tid & 63;
  const int wr = (w >> 1) * 64, wc = (w & 1) * 64;
  const int srow = tid >> 2, skoff = (tid & 3) * 8;
  const ushort* Ap = A + (size_t)(bm + srow) * K + skoff + koff;
  const ushort* Bp = Bt + (size_t)(bn + srow) * K + skoff + koff;
  const int lofs = w * 512;                 // wave-uniform LDS base (ushorts)
  const size_t half = (size_t)64 * K;
  const int fr = ln & 15, kg = ln >> 4;

  f32x4 acc[4][4];
  #pragma unroll
  for (int m = 0; m < 4; ++m)
    #pragma unroll
    for (int n = 0; n < 4; ++n) acc[m][n] = (f32x4){0.f, 0.f, 0.f, 0.f};

  // prologue: stage tile 0 into buf 0
  gload16(Ap,        &As[0][lofs]);
  gload16(Ap + half, &As[0][lofs + 2048]);
  gload16(Bp,        &Bs[0][lofs]);
  gload16(Bp + half, &Bs[0][lofs + 2048]);
  __syncthreads();

  const int nt = kspl >> 5;
  for (int t = 0; t < nt; ++t) {
    const int cur = t & 1;
    if (t + 1 < nt) {                       // stage next tile into other buf
      const int k1 = (t + 1) << 5;
      gload16(Ap + k1,        &As[cur ^ 1][lofs]);
      gload16(Ap + half + k1, &As[cur ^ 1][lofs + 2048]);
      gload16(Bp + k1,        &Bs[cur ^ 1][lofs]);
      gload16(Bp + half + k1, &Bs[cur ^ 1][lofs + 2048]);
    }
    short8x av[4], bv[4];
    #pragma unroll
    for (int m = 0; m < 4; ++m)
      av[m] = *(const short8x*)&As[cur][(wr + m*16 + fr)*32 + kg*8];
    #pragma unroll
    for (int n = 0; n < 4; ++n)
      bv[n] = *(const short8x*)&Bs[cur][(wc + n*16 + fr)*32 + kg*8];
    #pragma unroll
    for (int m = 0; m < 4; ++m)
      #pragma unroll
      for (int n = 0; n < 4; ++n)
        acc[m][n] = __builtin_amdgcn_mfma_f32_16x16x32_bf16(av[m], bv[n], acc[m][n], 0, 0, 0);
    __syncthreads();                        // drains stage loads + ds_reads
  }

  // C/D layout: col = lane&15, row = (lane>>4)*4 + reg   [m89-verified]
  if (EPI == 4) Cf += (size_t)blockIdx.z * ((size_t)MPAD * N);
  const int crow = bm + wr + kg*4;
  const int ccol = bn + wc + fr;
  float bi[4];
  #pragma unroll
  for (int n = 0; n < 4; ++n) bi[n] = (EPI == 4) ? 0.f : bias[ccol + n*16];
  #pragma unroll
  for (int m = 0; m < 4; ++m) {
    #pragma unroll
    for (int j = 0; j < 4; ++j) {
      const int r = crow + m*16 + j;
      if (r < M) {
        #pragma unroll
        for (int n = 0; n < 4; ++n) {
          const size_t off = (size_t)r * N + ccol + n*16;
          float vv = acc[m][n][j] + bi[n];
          if (EPI == 0) Cf[off] = vv;
          if (EPI == 1) Cf[off] = vv + R[off];
          if (EPI == 2) Cb[off] = f2bf(0.5f * vv * (1.f + erff(vv * 0.70710678118654752f)));
          if (EPI == 3) Cb[off] = f2bf(vv);
          if (EPI == 4) Cf[off] = vv;
        }
      }
    }
  }
}

// h[idx] += p0[idx] + p1[idx] + bias[col]   (split-K combine + residual)
__global__ void combine_k(const float* __restrict__ p0, const float* __restrict__ p1,
                          const float* __restrict__ bias, float* __restrict__ h) {
  const int idx = blockIdx.x * 256 + threadIdx.x;
  h[idx] += p0[idx] + p1[idx] + bias[idx % WD];
}

// ---------------------------------------------------------------------------
// Fused attention: one block = 64 q-rows (4 waves x 16) for one (b,h).
// K padded [208][72] and V^T [64][232] fully in LDS; P overlays K region.
// ---------------------------------------------------------------------------
__global__ __launch_bounds__(256) void attn_fused(
    const ushort* __restrict__ qkv,   // [6400][2304] : Q | K | V
    ushort* __restrict__ obf)         // [6400][768]
{
  __shared__ __align__(16) ushort KP[208*72];   // K, later P (4 x [16][232])
  __shared__ __align__(16) ushort Vt[64*232];
  const int tid = threadIdx.x;
  const int w = tid >> 6, l = tid & 63;
  const int fr = l & 15, kg = l >> 4;
  const int orig = blockIdx.y * 4 + blockIdx.x;
  const int id = (orig & 7) * 192 + (orig >> 3);
  const int qt = id & 3;
  const int bh = id >> 2;
  const int b = bh / 12, hh = bh - b*12;
  const size_t qrow0 = (size_t)b * SEQ;
  const ushort* kbase = qkv + qrow0*2304 + 768 + hh*64;
  const ushort* vbase = qkv + qrow0*2304 + 1536 + hh*64;

  #pragma unroll
  for (int it = 0; it < 7; ++it) {             // K: 208 rows x 64, zero-padded
    const int idx = it*256 + tid;
    if (idx < 1664) {
      const int row = idx >> 3, kc = (idx & 7) << 3;
      short8x v = (short8x){0,0,0,0,0,0,0,0};
      if (row < SEQ) v = *(const short8x*)(kbase + (size_t)row*2304 + kc);
      *(short8x*)&KP[row*72 + kc] = v;
    }
  }
  #pragma unroll
  for (int it = 0; it < 7; ++it) {             // V^T: 64 x 224, zero-padded
    const int t = it*32 + (tid & 31);
    const int dc = ((tid >> 5) & 7) << 3;
    short8x v = (short8x){0,0,0,0,0,0,0,0};
    if (t < SEQ) v = *(const short8x*)(vbase + (size_t)t*2304 + dc);
    #pragma unroll
    for (int j = 0; j < 8; ++j) Vt[(dc + j)*232 + t] = (ushort)v[j];
  }
  const int s_l = qt*64 + w*16 + fr;
  const ushort* qbase = qkv + (qrow0 + (s_l < SEQ ? s_l : SEQ-1))*2304 + hh*64;
  const short8x qf0 = *(const short8x*)(qbase + kg*8);
  const short8x qf1 = *(const short8x*)(qbase + 32 + kg*8);
  __syncthreads();

  // S = (Q K^T): 13 t-fragments of 16
  f32x4 sacc[13];
  #pragma unroll
  for (int f = 0; f < 13; ++f) sacc[f] = (f32x4){0.f,0.f,0.f,0.f};
  #pragma unroll
  for (int f = 0; f < 13; ++f) {
    const short8x kf0 = *(const short8x*)&KP[(f*16 + fr)*72 + kg*8];
    const short8x kf1 = *(const short8x*)&KP[(f*16 + fr)*72 + 32 + kg*8];
    sacc[f] = __builtin_amdgcn_mfma_f32_16x16x32_bf16(qf0, kf0, sacc[f], 0, 0, 0);
    sacc[f] = __builtin_amdgcn_mfma_f32_16x16x32_bf16(qf1, kf1, sacc[f], 0, 0, 0);
  }
  float mx[4] = {-1e30f,-1e30f,-1e30f,-1e30f};
  #pragma unroll
  for (int f = 0; f < 13; ++f)
    #pragma unroll
    for (int j = 0; j < 4; ++j) {
      float v = sacc[f][j] * 0.125f;
      if (f == 12 && fr >= 5) v = -1e30f;      // t >= 197 masked
      sacc[f][j] = v;
      mx[j] = fmaxf(mx[j], v);
    }
  #pragma unroll
  for (int j = 0; j < 4; ++j) {
    mx[j] = fmaxf(mx[j], __shfl_xor(mx[j], 1));
    mx[j] = fmaxf(mx[j], __shfl_xor(mx[j], 2));
    mx[j] = fmaxf(mx[j], __shfl_xor(mx[j], 4));
    mx[j] = fmaxf(mx[j], __shfl_xor(mx[j], 8));
  }
  float sm[4] = {0.f,0.f,0.f,0.f};
  #pragma unroll
  for (int f = 0; f < 13; ++f)
    #pragma unroll
    for (int j = 0; j < 4; ++j) {
      const float e = __expf(sacc[f][j] - mx[j]);
      sacc[f][j] = e; sm[j] += e;
    }
  #pragma unroll
  for (int j = 0; j < 4; ++j) {
    sm[j] += __shfl_xor(sm[j], 1);
    sm[j] += __shfl_xor(sm[j], 2);
    sm[j] += __shfl_xor(sm[j], 4);
    sm[j] += __shfl_xor(sm[j], 8);
    sm[j] = 1.f / sm[j];
  }
  __syncthreads();                              // everyone done reading K
  ushort* P = &KP[w*16*232];                    // per-wave P tile [16][232]
  #pragma unroll
  for (int f = 0; f < 13; ++f)
    #pragma unroll
    for (int j = 0; j < 4; ++j)
      P[(kg*4 + j)*232 + f*16 + fr] = f2bf(sacc[f][j] * sm[j]);
  #pragma unroll
  for (int j = 0; j < 4; ++j)
    P[(kg*4 + j)*232 + 208 + fr] = 0;           // zero pad t 208..223
  __syncthreads();

  short8x pf[7];
  #pragma unroll
  for (int tc = 0; tc < 7; ++tc)
    pf[tc] = *(const short8x*)&P[fr*232 + tc*32 + kg*8];
  f32x4 oacc[4];
  #pragma unroll
  for (int df = 0; df < 4; ++df) oacc[df] = (f32x4){0.f,0.f,0.f,0.f};
  #pragma unroll
  for (int df = 0; df < 4; ++df)
    #pragma unroll
    for (int tc = 0; tc < 7; ++tc) {
      const short8x vf = *(const short8x*)&Vt[(df*16 + fr)*232 + tc*32 + kg*8];
      oacc[df] = __builtin_amdgcn_mfma_f32_16x16x32_bf16(pf[tc], vf, oacc[df], 0, 0, 0);
    }
  #pragma unroll
  for (int df = 0; df < 4; ++df)
    #pragma unroll
    for (int j = 0; j < 4; ++j) {
      const int s = qt*64 + w*16 + kg*4 + j;
      if (s < SEQ)
        obf[(qrow0 + s)*768 + hh*64 + df*16 + fr] = f2bf(oacc[df][j]);
    }
}

// ---------------------------------------------------------------------------
__global__ void tcast_k(const float* __restrict__ in, ushort* __restrict__ out,
                        int K, int N) {
  __shared__ float t[32][33];
  const int bx = blockIdx.x * 32, by = blockIdx.y * 32;
  const int tx = threadIdx.x, ty = threadIdx.y;
  #pragma unroll
  for (int j = 0; j < 32; j += 8)
    t[ty + j][tx] = in[(size_t)(by + ty + j) * N + bx + tx];
  __syncthreads();
  #pragma unroll
  for (int j = 0; j < 32; j += 8)
    out[(size_t)(bx + ty + j) * K + by + tx] = f2bf(t[tx][ty + j]);
}

__global__ void tcast4_k(const float* __restrict__ s0, const float* __restrict__ s1,
                         const float* __restrict__ s2, const float* __restrict__ s3,
                         ushort* __restrict__ d0, ushort* __restrict__ d1,
                         ushort* __restrict__ d2, ushort* __restrict__ d3) {
  const int z = blockIdx.z;
  const float* s = (z == 0) ? s0 : (z == 1) ? s1 : (z == 2) ? s2 : s3;
  ushort* d = (z == 0) ? d0 : (z == 1) ? d1 : (z == 2) ? d2 : d3;
  __shared__ float t[32][33];
  const int bx = blockIdx.x * 32, by = blockIdx.y * 32;
  const int tx = threadIdx.x, ty = threadIdx.y;
  #pragma unroll
  for (int j = 0; j < 32; j += 8)
    t[ty + j][tx] = s[(size_t)(by + ty + j) * WD + bx + tx];
  __syncthreads();
  #pragma unroll
  for (int j = 0; j < 32; j += 8)
    d[(size_t)(bx + ty + j) * WD + by + tx] = f2bf(t[tx][ty + j]);
}

__global__ void castcv_k(const float* __restrict__ in, ushort* __restrict__ out) {
  const int i = blockIdx.x * 256 + threadIdx.x;
  out[i] = f2bf(in[i]);
}

__global__ void bcat_k(const float* __restrict__ a, const float* __restrict__ b,
                       const float* __restrict__ c, float* __restrict__ d) {
  const int i = blockIdx.x * 256 + threadIdx.x;
  if (i < 2304) d[i] = (i < 768) ? a[i] : (i < 1536) ? b[i - 768] : c[i - 1536];
}

__global__ void im2col_k(const float* __restrict__ x, ushort* __restrict__ A) {
  const int idx = blockIdx.x * 256 + threadIdx.x;
  if (idx >= PROWS * WD) return;
  const int k = idx % WD;
  const int row = idx / WD;
  const int pw = k & 15, ph = (k >> 4) & 15, c = k >> 8;
  const int px = row % 14, py = (row / 14) % 14, b = row / 196;
  A[idx] = f2bf(x[(size_t)((b*3 + c)*224 + py*16 + ph) * 224 + px*16 + pw]);
}

__global__ void assemble_k(const float* __restrict__ tok, const float* __restrict__ cls,
                           const float* __restrict__ pe, float* __restrict__ h) {
  const int idx = blockIdx.x * 256 + threadIdx.x;
  if (idx >= ROWS * WD) return;
  const int w = idx % WD;
  const int bs = idx / WD;
  const int s = bs % SEQ;
  const int b = bs / SEQ;
  float v;
  if (s == 0) v = cls[w];
  else        v = tok[(size_t)(b*196 + s - 1) * WD + w];
  h[idx] = v + pe[(size_t)s * WD + w];
}

__global__ __launch_bounds__(256) void layernorm_k(
    const float* __restrict__ x, const float* __restrict__ g,
    const float* __restrict__ bb, ushort* __restrict__ y)
{
  const int row = blockIdx.x;
  const int tid = threadIdx.x;
  const float* xr = x + (size_t)row * WD;
  const float v0 = xr[tid], v1 = xr[tid+256], v2 = xr[tid+512];
  __shared__ float red[4];
  float s = v0 + v1 + v2;
  s = wave_sum(s);
  const int wv = tid >> 6, ln = tid & 63;
  if (ln == 0) red[wv] = s;
  __syncthreads();
  const float mean = (red[0]+red[1]+red[2]+red[3]) * (1.f/768.f);
  const float d0 = v0-mean, d1 = v1-mean, d2 = v2-mean;
  float sq = d0*d0 + d1*d1 + d2*d2;
  sq = wave_sum(sq);
  __syncthreads();
  if (ln == 0) red[wv] = sq;
  __syncthreads();
  const float var = (red[0]+red[1]+red[2]+red[3]) * (1.f/768.f);
  const float inv = rsqrtf(var + 1e-5f);
  ushort* yr = y + (size_t)row * WD;
  yr[tid]     = f2bf(d0 * inv * g[tid]     + bb[tid]);
  yr[tid+256] = f2bf(d1 * inv * g[tid+256] + bb[tid+256]);
  yr[tid+512] = f2bf(d2 * inv * g[tid+512] + bb[tid+512]);
}

__global__ __launch_bounds__(256) void head_k(
    const float* __restrict__ h, const float* __restrict__ proj,
    float* __restrict__ out)
{
  const int b = blockIdx.x;
  const int tid = threadIdx.x;
  __shared__ float hr[768];
  __shared__ float red[4];
  const float* hrow = h + (size_t)b * SEQ * WD;
  hr[tid] = hrow[tid]; hr[tid+256] = hrow[tid+256]; hr[tid+512] = hrow[tid+512];
  __syncthreads();
  float o0 = 0.f, o1 = 0.f;
  for (int kx = 0; kx < 768; ++kx) {
    const float hv = hr[kx];
    o0 = fmaf(hv, proj[(size_t)kx*512 + tid],       o0);
    o1 = fmaf(hv, proj[(size_t)kx*512 + tid + 256], o1);
  }
  float sq = o0*o0 + o1*o1;
  sq = wave_sum(sq);
  const int wv = tid >> 6, ln = tid & 63;
  if (ln == 0) red[wv] = sq;
  __syncthreads();
  const float inv = 1.f / sqrtf(red[0]+red[1]+red[2]+red[3]);
  out[(size_t)b*512 + tid]       = o0 * inv;
  out[(size_t)b*512 + tid + 256] = o1 * inv;
}

// ---------------------------------------------------------------------------
extern "C" void kernel_launch(void* const* d_in, const int* in_sizes, int n_in,
                              void* d_out, int out_size, void* d_ws, size_t ws_size,
                              hipStream_t stream) {
  const float* x      = (const float*)d_in[0];
  const float* conv_w = (const float*)d_in[1];
  const float* conv_b = (const float*)d_in[2];
  const float* cls    = (const float*)d_in[3];
  const float* pe     = (const float*)d_in[4];
  const float* ln1_g  = (const float*)d_in[5];
  const float* ln1_b  = (const float*)d_in[6];
  const float* wq = (const float*)d_in[7];  const float* bq = (const float*)d_in[8];
  const float* wk = (const float*)d_in[9];  const float* bk = (const float*)d_in[10];
  const float* wvw = (const float*)d_in[11]; const float* bv = (const float*)d_in[12];
  const float* wo = (const float*)d_in[13]; const float* bo = (const float*)d_in[14];
  const float* ln2_g = (const float*)d_in[15]; const float* ln2_b = (const float*)d_in[16];
  const float* w1 = (const float*)d_in[17]; const float* b1 = (const float*)d_in[18];
  const float* w2 = (const float*)d_in[19]; const float* b2 = (const float*)d_in[20];
  const float* proj = (const float*)d_in[21];
  float* out = (float*)d_out;

  float* ws = (float*)d_ws;
  const size_t TOK = (size_t)ROWS * WD;          // 4,841,472 floats
  const size_t PPLANE = (size_t)MPAD * WD;       // partial-plane floats
  float* h = ws;
  float* part = h + TOK;                         // [2][6400][768] fp32
  ushort* ub = (ushort*)(part + 2*PPLANE);
  ushort* ybf    = ub;  ub += (size_t)MPAD * WD;        // [6400][768]
  ushort* qkv    = ub;  ub += (size_t)MPAD * 2304;      // [6400][2304]
  ushort* obf    = ub;  ub += (size_t)MPAD * WD;        // [6400][768]
  ushort* zbf    = ub;  ub += (size_t)MPAD * FF;        // [6400][3072]
  ushort* wt_qkv = ub;  ub += (size_t)2304 * WD;
  ushort* wt_o   = ub;  ub += (size_t)WD * WD;
  ushort* wt_1   = ub;  ub += (size_t)WD * FF;
  ushort* wt_2   = ub;  ub += (size_t)FF * WD;
  float* bqkv = (float*)ub;  ub += 4608;
  // patch-embed scratch overlays zbf: imbf [6272][768] bf16, then ypatch fp32
  ushort* imbf   = zbf;
  float*  ypatch = (float*)(zbf + (size_t)PROWS * WD);
  ushort* cbf    = wt_qkv;   // conv weights, pre-loop only

  // ---- patch embedding ----
  castcv_k<<<dim3(2304), dim3(256), 0, stream>>>(conv_w, cbf);
  im2col_k<<<dim3((PROWS*WD)/256), dim3(256), 0, stream>>>(x, imbf);
  gemm_bt<0><<<dim3(6, 49), dim3(256), 0, stream>>>(
      imbf, cbf, conv_b, nullptr, ypatch, nullptr, PROWS, WD, WD, WD);
  assemble_k<<<dim3((ROWS*WD)/256), dim3(256), 0, stream>>>(ypatch, cls, pe, h);

  const dim3 gqkv(18, 50);
  const dim3 gff(24, 50);
  const dim3 gsplit(6, 50, 2);
  const dim3 gattn(4, NB*NH);
  const dim3 gcomb((ROWS*WD)/256);
  const dim3 tdim(32, 8);

  for (int l = 0; l < NL; ++l) {
    const size_t wOff = (size_t)l * WD * WD;
    const size_t fOff = (size_t)l * WD * FF;
    const size_t vOff = (size_t)l * WD;
    const size_t fvOff = (size_t)l * FF;

    tcast4_k<<<dim3(24,24,4), tdim, 0, stream>>>(
        wq+wOff, wk+wOff, wvw+wOff, wo+wOff,
        wt_qkv, wt_qkv + 589824, wt_qkv + 1179648, wt_o);
    tcast_k<<<dim3(96,24), tdim, 0, stream>>>(w1+fOff, wt_1, WD, FF);
    tcast_k<<<dim3(24,96), tdim, 0, stream>>>(w2+fOff, wt_2, FF, WD);
    bcat_k<<<dim3(9), dim3(256), 0, stream>>>(bq+vOff, bk+vOff, bv+vOff, bqkv);

    layernorm_k<<<dim3(ROWS), dim3(256), 0, stream>>>(h, ln1_g+vOff, ln1_b+vOff, ybf);
    gemm_bt<3><<<gqkv, dim3(256), 0, stream>>>(ybf, wt_qkv, bqkv, nullptr,
                                               nullptr, qkv, ROWS, 2304, WD, WD);
    attn_fused<<<gattn, dim3(256), 0, stream>>>(qkv, obf);
    gemm_bt<4><<<gsplit, dim3(256), 0, stream>>>(obf, wt_o, nullptr, nullptr,
                                                 part, nullptr, ROWS, WD, WD, WD/2);
    combine_k<<<gcomb, dim3(256), 0, stream>>>(part, part + PPLANE, bo+vOff, h);
    layernorm_k<<<dim3(ROWS), dim3(256), 0, stream>>>(h, ln2_g+vOff, ln2_b+vOff, ybf);
    gemm_bt<2><<<gff, dim3(256), 0, stream>>>(ybf, wt_1, b1+fvOff, nullptr,
                                              nullptr, zbf, ROWS, FF, WD, WD);
    gemm_bt<4><<<gsplit, dim3(256), 0, stream>>>(zbf, wt_2, nullptr, nullptr,
                                                 part, nullptr, ROWS, WD, FF, FF/2);
    combine_k<<<gcomb, dim3(256), 0, stream>>>(part, part + PPLANE, b2+vOff, h);
  }

  head_k<<<dim3(NB), dim3(256), 0, stream>>>(h, proj, out);
}